// Round 7
// baseline (342.720 us; speedup 1.0000x reference)
//
#include <hip/hip_runtime.h>

#define N_PTS 8192
#define BATCH 2
#define KNN 8
#define NSLAB 128                  // 64-point slabs of the sorted arrays
#define CELLS 512                  // 8x8x8 Morton grid
#define NUNIT_C 4096               // chamfer wave-units: 4 combos x 1024 (8 rows)
#define NUNIT_S 8192               // smooth wave-units: 2 batches x 4096 (2 rows)
#define NUNITS  (NUNIT_C + NUNIT_S)
#define NBLOCKS 2048               // exactly resident at 8 blocks/CU; stealing fills

// workspace layout (float4 units):
//  [0 .. 6*8192)  sorted packed arrays float4(x,y,z,|p|^2)
//    arr 0,1: pc2[b] | arr 2,3: pc1+flow (warped) | arr 4,5: pc1
//  WS_BB0/WS_BB1: bbox min/max per [arr][slab]
//  WS_OIDX: u32[2][8192] sorted->orig for pc1;  WS_CTR: u32 work counter
#define ARR_PC2  0
#define ARR_WARP 2
#define ARR_PC1  4
#define WS_BB0   49152
#define WS_BB1   49920
#define WS_OIDX  50688
#define WS_CTR   54784             // float4 index; counter u32 at .x (byte 876544)

// ---------------- helpers ----------------
__device__ __forceinline__ void ce(unsigned &x, unsigned &y) {
    unsigned lo = min(x, y), hi = max(x, y); x = lo; y = hi;
}

__device__ __forceinline__ void insert4(unsigned o[4], unsigned key) {
    unsigned n0 = min(o[0], key);
    unsigned n1 = max(o[0], min(o[1], key));
    unsigned n2 = max(o[1], min(o[2], key));
    unsigned n3 = max(o[2], min(o[3], key));
    o[0]=n0; o[1]=n1; o[2]=n2; o[3]=n3;
}

__device__ __forceinline__ void merge_stage8(unsigned m[8], int d) {
    unsigned p[8], c[8];
    #pragma unroll
    for (int k = 0; k < 8; ++k) p[k] = (unsigned)__shfl_xor((int)m[k], d, 64);
    #pragma unroll
    for (int k = 0; k < 8; ++k) c[k] = min(m[k], p[7-k]);
    ce(c[0],c[4]); ce(c[1],c[5]); ce(c[2],c[6]); ce(c[3],c[7]);
    ce(c[0],c[2]); ce(c[1],c[3]); ce(c[4],c[6]); ce(c[5],c[7]);
    ce(c[0],c[1]); ce(c[2],c[3]); ce(c[4],c[5]); ce(c[6],c[7]);
    #pragma unroll
    for (int k = 0; k < 8; ++k) m[k] = c[k];
}

__device__ __forceinline__ void merge64(unsigned m[8]) {
    merge_stage8(m, 1); merge_stage8(m, 2); merge_stage8(m, 4);
    merge_stage8(m, 8); merge_stage8(m, 16); merge_stage8(m, 32);
}

// ordered-uint encode/decode for float atomicMin/Max on LDS
__device__ __forceinline__ unsigned f2o(float f) {
    unsigned u = __float_as_uint(f);
    return (u & 0x80000000u) ? ~u : (u | 0x80000000u);
}
__device__ __forceinline__ float o2f(unsigned u) {
    return __uint_as_float((u & 0x80000000u) ? (u ^ 0x80000000u) : ~u);
}

__device__ __forceinline__ unsigned spread3(unsigned v) {
    return ((v & 4u) << 4) | ((v & 2u) << 2) | (v & 1u);   // bits -> 6,3,0
}
__device__ __forceinline__ int cellof(float x, float y, float z) {
    int ix = min(7, max(0, (int)((x + 3.0f) * 1.3333333f)));
    int iy = min(7, max(0, (int)((y + 3.0f) * 1.3333333f)));
    int iz = min(7, max(0, (int)((z + 3.0f) * 1.3333333f)));
    return (int)((spread3((unsigned)ix) << 2) | (spread3((unsigned)iy) << 1)
                 | spread3((unsigned)iz));                  // 9-bit Morton
}

// squared distance point -> AABB (0 inside); exact lower bound for slab points
__device__ __forceinline__ float boxd2(const float4 bn, const float4 bx,
                                       float x, float y, float z) {
    float tx = fmaxf(fmaxf(bn.x - x, x - bx.x), 0.0f);     // v_max3
    float ty = fmaxf(fmaxf(bn.y - y, y - bx.y), 0.0f);
    float tz = fmaxf(fmaxf(bn.z - z, z - bx.z), 0.0f);
    return fmaf(tx, tx, fmaf(ty, ty, tz * tz));
}

// pop lowest slab id from the 128-bit {m0,m1} mask, -1 if empty
__device__ __forceinline__ int popslab(unsigned long long &m0, unsigned long long &m1) {
    if (m0) { int s = __ffsll(m0) - 1; m0 &= m0 - 1; return s; }
    if (m1) { int s = __ffsll(m1) - 1; m1 &= m1 - 1; return s + 64; }
    return -1;
}

// ---------------- pack+sort: 6 blocks, one array each ----------------
__global__ __launch_bounds__(512) void pack_sort_kernel(
        const float* __restrict__ pc1, const float* __restrict__ pc2,
        const float* __restrict__ flow, float4* __restrict__ ws,
        unsigned* __restrict__ oidx, unsigned* __restrict__ ctr) {
    __shared__ unsigned hist[CELLS];
    __shared__ unsigned offs[CELLS];
    __shared__ unsigned bbn[NSLAB * 3], bbx[NSLAB * 3];
    const int arr = blockIdx.x, t = threadIdx.x;
    const int bbatch = arr & 1;
    const bool warped = (arr >= 2 && arr < 4);
    const float* A = (arr < 2) ? pc2 : pc1;
    const size_t base = (size_t)bbatch * N_PTS * 3;

    if (arr == 0 && t == 0) ctr[0] = 0u;        // work counter for mega (each launch)

    for (int i = t; i < CELLS; i += 512) hist[i] = 0u;
    for (int i = t; i < NSLAB * 3; i += 512) { bbn[i] = 0xFFFFFFFFu; bbx[i] = 0u; }
    __syncthreads();

    int cid[16];
    #pragma unroll
    for (int k = 0; k < 16; ++k) {
        int i = t * 16 + k;
        float x = A[base + i*3+0], y = A[base + i*3+1], z = A[base + i*3+2];
        if (warped) { x += flow[base+i*3+0]; y += flow[base+i*3+1]; z += flow[base+i*3+2]; }
        cid[k] = cellof(x, y, z);
        atomicAdd(&hist[cid[k]], 1u);
    }
    __syncthreads();

    // exclusive scan of 512 bins by wave 0 (8 bins/lane + lane butterfly)
    if (t < 64) {
        unsigned loc[8], s = 0;
        #pragma unroll
        for (int q = 0; q < 8; ++q) { loc[q] = s; s += hist[t*8 + q]; }
        unsigned run = s;
        #pragma unroll
        for (int d = 1; d < 64; d <<= 1) {
            unsigned v = (unsigned)__shfl_up((int)run, d, 64);
            if (t >= d) run += v;
        }
        unsigned bse = run - s;
        #pragma unroll
        for (int q = 0; q < 8; ++q) offs[t*8 + q] = bse + loc[q];
    }
    __syncthreads();

    #pragma unroll
    for (int k = 0; k < 16; ++k) {
        int i = t * 16 + k;
        float x = A[base + i*3+0], y = A[base + i*3+1], z = A[base + i*3+2];
        if (warped) { x += flow[base+i*3+0]; y += flow[base+i*3+1]; z += flow[base+i*3+2]; }
        unsigned pos = atomicAdd(&offs[cid[k]], 1u);
        ws[(size_t)arr * N_PTS + pos] = make_float4(x, y, z, fmaf(x, x, fmaf(y, y, z*z)));
        if (arr >= 4) oidx[(size_t)(arr - 4) * N_PTS + pos] = (unsigned)i;
        int s = (int)(pos >> 6);
        atomicMin(&bbn[s*3+0], f2o(x)); atomicMax(&bbx[s*3+0], f2o(x));
        atomicMin(&bbn[s*3+1], f2o(y)); atomicMax(&bbx[s*3+1], f2o(y));
        atomicMin(&bbn[s*3+2], f2o(z)); atomicMax(&bbx[s*3+2], f2o(z));
    }
    __syncthreads();

    for (int s = t; s < NSLAB; s += 512) {
        ws[WS_BB0 + (size_t)arr * NSLAB + s] =
            make_float4(o2f(bbn[s*3+0]), o2f(bbn[s*3+1]), o2f(bbn[s*3+2]), 0.0f);
        ws[WS_BB1 + (size_t)arr * NSLAB + s] =
            make_float4(o2f(bbx[s*3+0]), o2f(bbx[s*3+1]), o2f(bbx[s*3+2]), 0.0f);
    }
}

// ---------------- mega: wave-stealing, prefetched slab-pruned exact scans ----------------
// R6 post-mortem: pruning cut VALU work (~18% measured) but VALUBusy fell to
// 62% (serial L2 latency in mask walks, no prefetch) and occupancy to 28.5%
// (heavy work spatially clustered -> all-heavy drain tail). R7:
// (1) 1-deep prefetch in every slab walk: one L2 latency per walk, not N;
// (2) wave-level work-stealing, x2749 bijective permute: temporal scatter of
//     heavy units, drain tail ~= one small unit;
// (3) chamfer seed from row-group centroid (1 butterfly, was 8); smooth seed
//     from own sorted slab (0 butterflies). Exactness: seed gives real ub;
//     skip slab only when AABB lb >= ub (chamfer) / >= thr_up (smooth, R6's
//     proven bucket gate); seed excluded from pass-2 (no double-insert).
__global__ __launch_bounds__(256, 4) void mega_kernel(
        const float4* __restrict__ ws, const float* __restrict__ flow,
        const unsigned* __restrict__ oidx, unsigned* __restrict__ ctr,
        float* __restrict__ out) {
    __shared__ float bacc;
    const int tid = threadIdx.x;
    const int lane = tid & 63;
    if (tid == 0) bacc = 0.0f;
    __syncthreads();

    for (;;) {
        unsigned got = 0;
        if (lane == 0) got = atomicAdd(ctr, 1u);
        got = (unsigned)__shfl((int)got, 0, 64);
        if (got >= NUNITS) break;
        const unsigned up = (got * 2749u) % (unsigned)NUNITS;   // bijective scatter

        if (up < NUNIT_C) {
            // ===== chamfer unit: 8 consecutive sorted rows =====
            const int z = (int)(up >> 10), bb = z & 1, dir = z >> 1;
            const int rbase = (int)(up & 1023) * 8;
            const int ca = (dir == 0 ? ARR_PC2 : ARR_WARP) + bb;
            const int ra = (dir == 0 ? ARR_WARP : ARR_PC2) + bb;
            const float4* rows = ws + (size_t)ra * N_PTS;
            const float4* cand = ws + (size_t)ca * N_PTS;
            const float4* bmn = ws + WS_BB0 + (size_t)ca * NSLAB;
            const float4* bmx = ws + WS_BB1 + (size_t)ca * NSLAB;

            float rx[8], ry[8], rz[8], bmin[8];
            float cx = 0.f, cy = 0.f, cz = 0.f;
            #pragma unroll
            for (int k = 0; k < 8; ++k) {
                float4 q = rows[rbase + k];          // wave-uniform broadcast
                rx[k] = q.x; ry[k] = q.y; rz[k] = q.z;
                cx += q.x; cy += q.y; cz += q.z;
                bmin[k] = __builtin_inff();
            }
            cx *= 0.125f; cy *= 0.125f; cz *= 0.125f;

            float4 bn0 = bmn[lane], bx0 = bmx[lane];
            float4 bn1 = bmn[lane + 64], bx1 = bmx[lane + 64];
            float lb0[8], lb1[8];
            #pragma unroll
            for (int k = 0; k < 8; ++k) {
                lb0[k] = boxd2(bn0, bx0, rx[k], ry[k], rz[k]);
                lb1[k] = boxd2(bn1, bx1, rx[k], ry[k], rz[k]);
            }
            // centroid argmin slab -> single seed (rows are sorted-adjacent)
            float cl0 = boxd2(bn0, bx0, cx, cy, cz);
            float cl1 = boxd2(bn1, bx1, cx, cy, cz);
            unsigned kk = min((__float_as_uint(cl0) & 0xFFFFFF80u) | (unsigned)lane,
                              (__float_as_uint(cl1) & 0xFFFFFF80u) | (unsigned)(lane + 64));
            #pragma unroll
            for (int d = 1; d < 64; d <<= 1)
                kk = min(kk, (unsigned)__shfl_xor((int)kk, d, 64));
            const int sseed = (int)(kk & 127u);
            {   // seed scan: real distances -> ub
                float4 c = cand[sseed * 64 + lane];
                #pragma unroll
                for (int k = 0; k < 8; ++k) {
                    float dx = rx[k]-c.x, dy = ry[k]-c.y, dz = rz[k]-c.z;
                    bmin[k] = fminf(bmin[k], fmaf(dx, dx, fmaf(dy, dy, dz*dz)));
                }
            }
            #pragma unroll
            for (int k = 0; k < 8; ++k) {            // wave-min ub per row
                #pragma unroll
                for (int d = 1; d < 64; d <<= 1)
                    bmin[k] = fminf(bmin[k], __shfl_xor(bmin[k], d, 64));
            }
            bool p0 = false, p1 = false;
            #pragma unroll
            for (int k = 0; k < 8; ++k) { p0 |= (lb0[k] < bmin[k]); p1 |= (lb1[k] < bmin[k]); }
            unsigned long long q0 = __ballot(p0), q1 = __ballot(p1);
            if (sseed < 64) q0 &= ~(1ull << sseed); else q1 &= ~(1ull << (sseed - 64));

            // prefetched walk: load slab i+1 while computing slab i
            int s = popslab(q0, q1);
            if (s >= 0) {
                float4 c = cand[s * 64 + lane];
                for (;;) {
                    int sn = popslab(q0, q1);
                    float4 cn;
                    if (sn >= 0) cn = cand[sn * 64 + lane];
                    #pragma unroll
                    for (int k = 0; k < 8; ++k) {
                        float dx = rx[k]-c.x, dy = ry[k]-c.y, dz = rz[k]-c.z;
                        bmin[k] = fminf(bmin[k], fmaf(dx, dx, fmaf(dy, dy, dz*dz)));
                    }
                    if (sn < 0) break;
                    c = cn;
                }
            }
            #pragma unroll
            for (int k = 0; k < 8; ++k) {            // final wave-min per row
                #pragma unroll
                for (int d = 1; d < 64; d <<= 1)
                    bmin[k] = fminf(bmin[k], __shfl_xor(bmin[k], d, 64));
            }
            if (lane == 0) {
                float val = 0.0f;
                #pragma unroll
                for (int k = 0; k < 8; ++k) val += sqrtf(fmaxf(bmin[k], 0.0f));
                atomicAdd(&bacc, val * (1.0f / (float)(BATCH * N_PTS)));
            }
        } else {
            // ===== smooth unit: 2 consecutive sorted rows, exact top-8 =====
            const int su = (int)(up - NUNIT_C);
            const int b = su >> 12;
            const int i0w = (su & 4095) * 2;
            const float4* cand = ws + (size_t)(ARR_PC1 + b) * N_PTS;
            const float4* bmn = ws + WS_BB0 + (size_t)(ARR_PC1 + b) * NSLAB;
            const float4* bmx = ws + WS_BB1 + (size_t)(ARR_PC1 + b) * NSLAB;
            const unsigned* OI = oidx + (size_t)b * N_PTS;
            const float* F = flow + (size_t)b * N_PTS * 3;

            float rx[2], ry[2], rz[2], thrf[2];
            unsigned o[2][4];
            #pragma unroll
            for (int r = 0; r < 2; ++r) {
                float4 q = cand[i0w + r];            // wave-uniform
                rx[r] = q.x; ry[r] = q.y; rz[r] = q.z;
                #pragma unroll
                for (int k = 0; k < 4; ++k) o[r][k] = 0xFFFFFFFFu;
            }
            float4 bn0 = bmn[lane], bx0 = bmx[lane];
            float4 bn1 = bmn[lane + 64], bx1 = bmx[lane + 64];
            float lb0[2], lb1[2];
            #pragma unroll
            for (int r = 0; r < 2; ++r) {
                lb0[r] = boxd2(bn0, bx0, rx[r], ry[r], rz[r]);
                lb1[r] = boxd2(bn1, bx1, rx[r], ry[r], rz[r]);
            }
            const int sown = i0w >> 6;               // own slab = natural seed
            {
                float4 c = cand[sown * 64 + lane];
                int j = sown * 64 + lane;
                #pragma unroll
                for (int r = 0; r < 2; ++r) {
                    float dx = rx[r]-c.x, dy = ry[r]-c.y, dz = rz[r]-c.z;
                    float d2 = fmaf(dx, dx, fmaf(dy, dy, dz*dz));
                    unsigned key = (__float_as_uint(d2) & 0xFFFFE000u) | (unsigned)j;
                    key = (j == i0w + r) ? 0xFFFFFFFFu : key;
                    insert4(o[r], key);
                }
            }
            // tight thr: per-32-half true top-4 butterfly; bound = max of the
            // halves' 4th keys (8 distinct real keys >= true 8th); thr_up with
            // +2 truncation-bucket slack strictly exceeds d2 of any key<=thr
            #pragma unroll
            for (int r = 0; r < 2; ++r) {
                unsigned m0 = o[r][0], m1 = o[r][1], m2 = o[r][2], m3 = o[r][3];
                #pragma unroll
                for (int d = 1; d <= 16; d <<= 1) {
                    unsigned a0 = (unsigned)__shfl_xor((int)m0, d, 64);
                    unsigned a1 = (unsigned)__shfl_xor((int)m1, d, 64);
                    unsigned a2 = (unsigned)__shfl_xor((int)m2, d, 64);
                    unsigned a3 = (unsigned)__shfl_xor((int)m3, d, 64);
                    unsigned c0 = min(m0, a3), c1 = min(m1, a2);
                    unsigned c2 = min(m2, a1), c3 = min(m3, a0);
                    ce(c0, c2); ce(c1, c3); ce(c0, c1); ce(c2, c3);
                    m0 = c0; m1 = c1; m2 = c2; m3 = c3;
                }
                unsigned bound = max(m3, (unsigned)__shfl_xor((int)m3, 32, 64));
                thrf[r] = __uint_as_float((bound & 0xFFFFE000u) + 0x4000u);
            }
            bool p0 = (lb0[0] < thrf[0]) | (lb0[1] < thrf[1]);
            bool p1 = (lb1[0] < thrf[0]) | (lb1[1] < thrf[1]);
            unsigned long long q0 = __ballot(p0), q1 = __ballot(p1);
            if (sown < 64) q0 &= ~(1ull << sown); else q1 &= ~(1ull << (sown - 64));

            int s = popslab(q0, q1);
            if (s >= 0) {
                float4 c = cand[s * 64 + lane];
                int j = s * 64 + lane;
                for (;;) {
                    int sn = popslab(q0, q1);
                    float4 cn; int jn = 0;
                    if (sn >= 0) { cn = cand[sn * 64 + lane]; jn = sn * 64 + lane; }
                    #pragma unroll
                    for (int r = 0; r < 2; ++r) {
                        float dx = rx[r]-c.x, dy = ry[r]-c.y, dz = rz[r]-c.z;
                        float d2 = fmaf(dx, dx, fmaf(dy, dy, dz*dz));
                        unsigned key = (__float_as_uint(d2) & 0xFFFFE000u) | (unsigned)j;
                        key = (j == i0w + r) ? 0xFFFFFFFFu : key;
                        insert4(o[r], key);
                    }
                    if (sn < 0) break;
                    c = cn; j = jn;
                }
            }

            // final per-point top-8 + epilogue (sel over 16 lanes, dup x4 -> /4)
            const int sel = lane & 15;
            const int pr = sel >> 3, kq = sel & 7;
            unsigned mykey = 0xFFFFFFFFu;
            #pragma unroll
            for (int r = 0; r < 2; ++r) {
                unsigned m[8] = {o[r][0], o[r][1], o[r][2], o[r][3],
                                 0xFFFFFFFFu, 0xFFFFFFFFu, 0xFFFFFFFFu, 0xFFFFFFFFu};
                merge64(m);
                if (pr == r) {
                    unsigned k2 = m[0];
                    #pragma unroll
                    for (int t2 = 1; t2 < 8; ++t2) k2 = (kq == t2) ? m[t2] : k2;
                    mykey = k2;
                }
            }
            const int isrt = i0w + pr;
            const int io = (int)OI[isrt];
            const int j  = (int)(mykey & (N_PTS - 1));
            const int jo = (int)OI[j];
            float dx = F[io*3+0] - F[jo*3+0];
            float dy = F[io*3+1] - F[jo*3+1];
            float dz = F[io*3+2] - F[jo*3+2];
            float sv = sqrtf(fmaf(dx, dx, fmaf(dy, dy, dz * dz)));
            #pragma unroll
            for (int d = 1; d < 64; d <<= 1) sv += __shfl_xor(sv, d, 64);
            if (lane == 0)
                atomicAdd(&bacc, sv * (0.125f / ((float)BATCH * N_PTS * KNN)));
        }
    }

    __syncthreads();
    if (tid == 0) atomicAdd(out, bacc);
}

extern "C" void kernel_launch(void* const* d_in, const int* in_sizes, int n_in,
                              void* d_out, int out_size, void* d_ws, size_t ws_size,
                              hipStream_t stream) {
    const float* pc1  = (const float*)d_in[0];
    const float* pc2  = (const float*)d_in[1];
    const float* flow = (const float*)d_in[2];
    float* out = (float*)d_out;
    float4* ws4 = (float4*)d_ws;                      // needs ~857 KiB + 16B
    unsigned* oidx = (unsigned*)(ws4 + WS_OIDX);
    unsigned* ctr  = (unsigned*)(ws4 + WS_CTR);

    pack_sort_kernel<<<dim3(6), 512, 0, stream>>>(pc1, pc2, flow, ws4, oidx, ctr);
    mega_kernel<<<dim3(NBLOCKS), 256, 0, stream>>>(ws4, flow, oidx, ctr, out);
}

// Round 8
// 230.750 us; speedup vs baseline: 1.4852x; 1.4852x over previous
//
#include <hip/hip_runtime.h>

#define N_PTS 8192
#define BATCH 2
#define KNN 8
#define NSLAB 128                  // 64-point slabs of the sorted arrays
#define CELLS 512                  // 8x8x8 Morton grid
#define NUNIT_C 4096               // chamfer wave-units: 4 combos x 1024 (8 rows)
#define NUNIT_S 8192               // smooth wave-units: 2 batches x 4096 (2 rows)
#define NUNITS  (NUNIT_C + NUNIT_S)
#define NBLOCKS 1536               // 6144 waves x exactly 2 units: {w, w+6144}

// workspace layout (float4 units):
//  [0 .. 6*8192)  sorted packed arrays float4(x,y,z,|p|^2)
//    arr 0,1: pc2[b] | arr 2,3: pc1+flow (warped) | arr 4,5: pc1
//  WS_BB0/WS_BB1: bbox min/max per [arr][slab]
//  WS_OIDX: u32[2][8192] sorted->orig for pc1
#define ARR_PC2  0
#define ARR_WARP 2
#define ARR_PC1  4
#define WS_BB0   49152
#define WS_BB1   49920
#define WS_OIDX  50688

// ---------------- helpers ----------------
__device__ __forceinline__ void ce(unsigned &x, unsigned &y) {
    unsigned lo = min(x, y), hi = max(x, y); x = lo; y = hi;
}

__device__ __forceinline__ void insert4(unsigned o[4], unsigned key) {
    unsigned n0 = min(o[0], key);
    unsigned n1 = max(o[0], min(o[1], key));
    unsigned n2 = max(o[1], min(o[2], key));
    unsigned n3 = max(o[2], min(o[3], key));
    o[0]=n0; o[1]=n1; o[2]=n2; o[3]=n3;
}

__device__ __forceinline__ void merge_stage8(unsigned m[8], int d) {
    unsigned p[8], c[8];
    #pragma unroll
    for (int k = 0; k < 8; ++k) p[k] = (unsigned)__shfl_xor((int)m[k], d, 64);
    #pragma unroll
    for (int k = 0; k < 8; ++k) c[k] = min(m[k], p[7-k]);
    ce(c[0],c[4]); ce(c[1],c[5]); ce(c[2],c[6]); ce(c[3],c[7]);
    ce(c[0],c[2]); ce(c[1],c[3]); ce(c[4],c[6]); ce(c[5],c[7]);
    ce(c[0],c[1]); ce(c[2],c[3]); ce(c[4],c[5]); ce(c[6],c[7]);
    #pragma unroll
    for (int k = 0; k < 8; ++k) m[k] = c[k];
}

__device__ __forceinline__ void merge64(unsigned m[8]) {
    merge_stage8(m, 1); merge_stage8(m, 2); merge_stage8(m, 4);
    merge_stage8(m, 8); merge_stage8(m, 16); merge_stage8(m, 32);
}

// ordered-uint encode/decode for float atomicMin/Max on LDS
__device__ __forceinline__ unsigned f2o(float f) {
    unsigned u = __float_as_uint(f);
    return (u & 0x80000000u) ? ~u : (u | 0x80000000u);
}
__device__ __forceinline__ float o2f(unsigned u) {
    return __uint_as_float((u & 0x80000000u) ? (u ^ 0x80000000u) : ~u);
}

__device__ __forceinline__ unsigned spread3(unsigned v) {
    return ((v & 4u) << 4) | ((v & 2u) << 2) | (v & 1u);   // bits -> 6,3,0
}
__device__ __forceinline__ int cellof(float x, float y, float z) {
    int ix = min(7, max(0, (int)((x + 3.0f) * 1.3333333f)));
    int iy = min(7, max(0, (int)((y + 3.0f) * 1.3333333f)));
    int iz = min(7, max(0, (int)((z + 3.0f) * 1.3333333f)));
    return (int)((spread3((unsigned)ix) << 2) | (spread3((unsigned)iy) << 1)
                 | spread3((unsigned)iz));                  // 9-bit Morton
}

// squared distance point -> AABB (0 inside); exact lower bound for slab points
__device__ __forceinline__ float boxd2(const float4 bn, const float4 bx,
                                       float x, float y, float z) {
    float tx = fmaxf(fmaxf(bn.x - x, x - bx.x), 0.0f);     // v_max3
    float ty = fmaxf(fmaxf(bn.y - y, y - bx.y), 0.0f);
    float tz = fmaxf(fmaxf(bn.z - z, z - bx.z), 0.0f);
    return fmaf(tx, tx, fmaf(ty, ty, tz * tz));
}

// pop lowest slab id from the 128-bit {m0,m1} mask, -1 if empty
__device__ __forceinline__ int popslab(unsigned long long &m0, unsigned long long &m1) {
    if (m0) { int s = __ffsll(m0) - 1; m0 &= m0 - 1; return s; }
    if (m1) { int s = __ffsll(m1) - 1; m1 &= m1 - 1; return s + 64; }
    return -1;
}

// ---------------- pack+sort: 6 blocks, one array each ----------------
__global__ __launch_bounds__(512) void pack_sort_kernel(
        const float* __restrict__ pc1, const float* __restrict__ pc2,
        const float* __restrict__ flow, float4* __restrict__ ws,
        unsigned* __restrict__ oidx) {
    __shared__ unsigned hist[CELLS];
    __shared__ unsigned offs[CELLS];
    __shared__ unsigned bbn[NSLAB * 3], bbx[NSLAB * 3];
    const int arr = blockIdx.x, t = threadIdx.x;
    const int bbatch = arr & 1;
    const bool warped = (arr >= 2 && arr < 4);
    const float* A = (arr < 2) ? pc2 : pc1;
    const size_t base = (size_t)bbatch * N_PTS * 3;

    for (int i = t; i < CELLS; i += 512) hist[i] = 0u;
    for (int i = t; i < NSLAB * 3; i += 512) { bbn[i] = 0xFFFFFFFFu; bbx[i] = 0u; }
    __syncthreads();

    int cid[16];
    #pragma unroll
    for (int k = 0; k < 16; ++k) {
        int i = t * 16 + k;
        float x = A[base + i*3+0], y = A[base + i*3+1], z = A[base + i*3+2];
        if (warped) { x += flow[base+i*3+0]; y += flow[base+i*3+1]; z += flow[base+i*3+2]; }
        cid[k] = cellof(x, y, z);
        atomicAdd(&hist[cid[k]], 1u);
    }
    __syncthreads();

    // exclusive scan of 512 bins by wave 0 (8 bins/lane + lane butterfly)
    if (t < 64) {
        unsigned loc[8], s = 0;
        #pragma unroll
        for (int q = 0; q < 8; ++q) { loc[q] = s; s += hist[t*8 + q]; }
        unsigned run = s;
        #pragma unroll
        for (int d = 1; d < 64; d <<= 1) {
            unsigned v = (unsigned)__shfl_up((int)run, d, 64);
            if (t >= d) run += v;
        }
        unsigned bse = run - s;
        #pragma unroll
        for (int q = 0; q < 8; ++q) offs[t*8 + q] = bse + loc[q];
    }
    __syncthreads();

    #pragma unroll
    for (int k = 0; k < 16; ++k) {
        int i = t * 16 + k;
        float x = A[base + i*3+0], y = A[base + i*3+1], z = A[base + i*3+2];
        if (warped) { x += flow[base+i*3+0]; y += flow[base+i*3+1]; z += flow[base+i*3+2]; }
        unsigned pos = atomicAdd(&offs[cid[k]], 1u);
        ws[(size_t)arr * N_PTS + pos] = make_float4(x, y, z, fmaf(x, x, fmaf(y, y, z*z)));
        if (arr >= 4) oidx[(size_t)(arr - 4) * N_PTS + pos] = (unsigned)i;
        int s = (int)(pos >> 6);
        atomicMin(&bbn[s*3+0], f2o(x)); atomicMax(&bbx[s*3+0], f2o(x));
        atomicMin(&bbn[s*3+1], f2o(y)); atomicMax(&bbx[s*3+1], f2o(y));
        atomicMin(&bbn[s*3+2], f2o(z)); atomicMax(&bbx[s*3+2], f2o(z));
    }
    __syncthreads();

    for (int s = t; s < NSLAB; s += 512) {
        ws[WS_BB0 + (size_t)arr * NSLAB + s] =
            make_float4(o2f(bbn[s*3+0]), o2f(bbn[s*3+1]), o2f(bbn[s*3+2]), 0.0f);
        ws[WS_BB1 + (size_t)arr * NSLAB + s] =
            make_float4(o2f(bbx[s*3+0]), o2f(bbx[s*3+1]), o2f(bbx[s*3+2]), 0.0f);
    }
}

// ---------------- per-wave units (straight-line, no persistent loop state) ----------------
// chamfer unit: 8 consecutive sorted rows, slab-pruned exact min.
// Seeds: per-row argmin-lb slabs (R6, tight ub). Walks: 1-deep prefetch (R7).
__device__ __forceinline__ float chamfer_unit(const float4* __restrict__ ws,
                                              int cu, int lane) {
    const int z = cu >> 10, bb = z & 1, dir = z >> 1;
    const int rbase = (cu & 1023) * 8;
    const int ca = (dir == 0 ? ARR_PC2 : ARR_WARP) + bb;
    const int ra = (dir == 0 ? ARR_WARP : ARR_PC2) + bb;
    const float4* rows = ws + (size_t)ra * N_PTS;
    const float4* cand = ws + (size_t)ca * N_PTS;
    const float4* bmn = ws + WS_BB0 + (size_t)ca * NSLAB;
    const float4* bmx = ws + WS_BB1 + (size_t)ca * NSLAB;

    float rx[8], ry[8], rz[8], bmin[8];
    #pragma unroll
    for (int k = 0; k < 8; ++k) {
        float4 q = rows[rbase + k];              // wave-uniform broadcast
        rx[k] = q.x; ry[k] = q.y; rz[k] = q.z;
        bmin[k] = __builtin_inff();
    }
    float4 bn0 = bmn[lane], bx0 = bmx[lane];
    float4 bn1 = bmn[lane + 64], bx1 = bmx[lane + 64];
    float lb0[8], lb1[8];
    unsigned long long sm0 = 0ull, sm1 = 0ull;
    #pragma unroll
    for (int k = 0; k < 8; ++k) {
        lb0[k] = boxd2(bn0, bx0, rx[k], ry[k], rz[k]);
        lb1[k] = boxd2(bn1, bx1, rx[k], ry[k], rz[k]);
        unsigned k0 = (__float_as_uint(lb0[k]) & 0xFFFFFF80u) | (unsigned)lane;
        unsigned k1 = (__float_as_uint(lb1[k]) & 0xFFFFFF80u) | (unsigned)(lane + 64);
        unsigned kk = min(k0, k1);
        #pragma unroll
        for (int d = 1; d < 64; d <<= 1)
            kk = min(kk, (unsigned)__shfl_xor((int)kk, d, 64));
        unsigned s = kk & 127u;
        if (s < 64) sm0 |= 1ull << s; else sm1 |= 1ull << (s - 64);
    }
    // seed walk (>=1 slab guaranteed), 1-deep prefetch
    unsigned long long t0 = sm0, t1 = sm1;
    int s = popslab(t0, t1);
    float4 c = cand[s * 64 + lane];
    for (;;) {
        int sn = popslab(t0, t1);
        float4 cn;
        if (sn >= 0) cn = cand[sn * 64 + lane];
        #pragma unroll
        for (int k = 0; k < 8; ++k) {
            float dx = rx[k]-c.x, dy = ry[k]-c.y, dz = rz[k]-c.z;
            bmin[k] = fminf(bmin[k], fmaf(dx, dx, fmaf(dy, dy, dz*dz)));
        }
        if (sn < 0) break;
        c = cn;
    }
    // wave-reduced ub per row -> pass-2 mask (exclude seeds)
    bool p0 = false, p1 = false;
    #pragma unroll
    for (int k = 0; k < 8; ++k) {
        float u = bmin[k];
        #pragma unroll
        for (int d = 1; d < 64; d <<= 1)
            u = fminf(u, __shfl_xor(u, d, 64));
        bmin[k] = u;
        p0 |= (lb0[k] < u); p1 |= (lb1[k] < u);
    }
    unsigned long long q0 = __ballot(p0) & ~sm0;
    unsigned long long q1 = __ballot(p1) & ~sm1;
    s = popslab(q0, q1);
    if (s >= 0) {
        c = cand[s * 64 + lane];
        for (;;) {
            int sn = popslab(q0, q1);
            float4 cn;
            if (sn >= 0) cn = cand[sn * 64 + lane];
            #pragma unroll
            for (int k = 0; k < 8; ++k) {
                float dx = rx[k]-c.x, dy = ry[k]-c.y, dz = rz[k]-c.z;
                bmin[k] = fminf(bmin[k], fmaf(dx, dx, fmaf(dy, dy, dz*dz)));
            }
            if (sn < 0) break;
            c = cn;
        }
        #pragma unroll
        for (int k = 0; k < 8; ++k) {
            #pragma unroll
            for (int d = 1; d < 64; d <<= 1)
                bmin[k] = fminf(bmin[k], __shfl_xor(bmin[k], d, 64));
        }
    }
    float val = 0.0f;
    if (lane == 0) {
        #pragma unroll
        for (int k = 0; k < 8; ++k) val += sqrtf(fmaxf(bmin[k], 0.0f));
    }
    return val;                                   // nonzero on lane 0 only
}

// smooth unit: 2 consecutive sorted rows, slab-pruned exact top-8.
// Seeds: own slab + per-row argmin slab; thr via proven butterfly bound.
__device__ __forceinline__ float smooth_unit(const float4* __restrict__ ws,
                                             const unsigned* __restrict__ oidx,
                                             const float* __restrict__ flow,
                                             int su, int lane) {
    const int b = su >> 12;
    const int i0w = (su & 4095) * 2;
    const float4* cand = ws + (size_t)(ARR_PC1 + b) * N_PTS;
    const float4* bmn = ws + WS_BB0 + (size_t)(ARR_PC1 + b) * NSLAB;
    const float4* bmx = ws + WS_BB1 + (size_t)(ARR_PC1 + b) * NSLAB;
    const unsigned* OI = oidx + (size_t)b * N_PTS;
    const float* F = flow + (size_t)b * N_PTS * 3;

    float rx[2], ry[2], rz[2], thrf[2];
    unsigned o[2][4];
    #pragma unroll
    for (int r = 0; r < 2; ++r) {
        float4 q = cand[i0w + r];                 // wave-uniform
        rx[r] = q.x; ry[r] = q.y; rz[r] = q.z;
        #pragma unroll
        for (int k = 0; k < 4; ++k) o[r][k] = 0xFFFFFFFFu;
    }
    float4 bn0 = bmn[lane], bx0 = bmx[lane];
    float4 bn1 = bmn[lane + 64], bx1 = bmx[lane + 64];
    float lb0[2], lb1[2];
    unsigned long long sm0 = 0ull, sm1 = 0ull;
    { int so = i0w >> 6;                          // own slab always seeded
      if (so < 64) sm0 |= 1ull << so; else sm1 |= 1ull << (so - 64); }
    #pragma unroll
    for (int r = 0; r < 2; ++r) {
        lb0[r] = boxd2(bn0, bx0, rx[r], ry[r], rz[r]);
        lb1[r] = boxd2(bn1, bx1, rx[r], ry[r], rz[r]);
        unsigned k0 = (__float_as_uint(lb0[r]) & 0xFFFFFF80u) | (unsigned)lane;
        unsigned k1 = (__float_as_uint(lb1[r]) & 0xFFFFFF80u) | (unsigned)(lane + 64);
        unsigned kk = min(k0, k1);
        #pragma unroll
        for (int d = 1; d < 64; d <<= 1)
            kk = min(kk, (unsigned)__shfl_xor((int)kk, d, 64));
        unsigned s = kk & 127u;
        if (s < 64) sm0 |= 1ull << s; else sm1 |= 1ull << (s - 64);
    }
    // seed walk with prefetch + insert
    unsigned long long t0 = sm0, t1 = sm1;
    int s = popslab(t0, t1);
    float4 c = cand[s * 64 + lane];
    int j = s * 64 + lane;
    for (;;) {
        int sn = popslab(t0, t1);
        float4 cn; int jn = 0;
        if (sn >= 0) { cn = cand[sn * 64 + lane]; jn = sn * 64 + lane; }
        #pragma unroll
        for (int r = 0; r < 2; ++r) {
            float dx = rx[r]-c.x, dy = ry[r]-c.y, dz = rz[r]-c.z;
            float d2 = fmaf(dx, dx, fmaf(dy, dy, dz*dz));
            unsigned key = (__float_as_uint(d2) & 0xFFFFE000u) | (unsigned)j;
            key = (j == i0w + r) ? 0xFFFFFFFFu : key;     // self-exclusion
            insert4(o[r], key);
        }
        if (sn < 0) break;
        c = cn; j = jn;
    }
    // tight thr: per-32-half true top-4 butterfly; bound = max of halves' 4th
    // keys (8 distinct real keys >= true 8th); +2 truncation-bucket slack
    #pragma unroll
    for (int r = 0; r < 2; ++r) {
        unsigned m0 = o[r][0], m1 = o[r][1], m2 = o[r][2], m3 = o[r][3];
        #pragma unroll
        for (int d = 1; d <= 16; d <<= 1) {
            unsigned a0 = (unsigned)__shfl_xor((int)m0, d, 64);
            unsigned a1 = (unsigned)__shfl_xor((int)m1, d, 64);
            unsigned a2 = (unsigned)__shfl_xor((int)m2, d, 64);
            unsigned a3 = (unsigned)__shfl_xor((int)m3, d, 64);
            unsigned c0 = min(m0, a3), c1 = min(m1, a2);
            unsigned c2 = min(m2, a1), c3 = min(m3, a0);
            ce(c0, c2); ce(c1, c3); ce(c0, c1); ce(c2, c3);
            m0 = c0; m1 = c1; m2 = c2; m3 = c3;
        }
        unsigned bound = max(m3, (unsigned)__shfl_xor((int)m3, 32, 64));
        thrf[r] = __uint_as_float((bound & 0xFFFFE000u) + 0x4000u);
    }
    bool p0 = (lb0[0] < thrf[0]) | (lb0[1] < thrf[1]);
    bool p1 = (lb1[0] < thrf[0]) | (lb1[1] < thrf[1]);
    unsigned long long q0 = __ballot(p0) & ~sm0;
    unsigned long long q1 = __ballot(p1) & ~sm1;
    s = popslab(q0, q1);
    if (s >= 0) {
        c = cand[s * 64 + lane]; j = s * 64 + lane;
        for (;;) {
            int sn = popslab(q0, q1);
            float4 cn; int jn = 0;
            if (sn >= 0) { cn = cand[sn * 64 + lane]; jn = sn * 64 + lane; }
            #pragma unroll
            for (int r = 0; r < 2; ++r) {
                float dx = rx[r]-c.x, dy = ry[r]-c.y, dz = rz[r]-c.z;
                float d2 = fmaf(dx, dx, fmaf(dy, dy, dz*dz));
                unsigned key = (__float_as_uint(d2) & 0xFFFFE000u) | (unsigned)j;
                key = (j == i0w + r) ? 0xFFFFFFFFu : key;
                insert4(o[r], key);
            }
            if (sn < 0) break;
            c = cn; j = jn;
        }
    }
    // final per-point top-8 + epilogue (sel over 16 lanes, dup x4 -> /4 in scale)
    const int sel = lane & 15;
    const int pr = sel >> 3, kq = sel & 7;
    unsigned mykey = 0xFFFFFFFFu;
    #pragma unroll
    for (int r = 0; r < 2; ++r) {
        unsigned m[8] = {o[r][0], o[r][1], o[r][2], o[r][3],
                         0xFFFFFFFFu, 0xFFFFFFFFu, 0xFFFFFFFFu, 0xFFFFFFFFu};
        merge64(m);
        if (pr == r) {
            unsigned k2 = m[0];
            #pragma unroll
            for (int t2 = 1; t2 < 8; ++t2) k2 = (kq == t2) ? m[t2] : k2;
            mykey = k2;
        }
    }
    const int isrt = i0w + pr;
    const int io = (int)OI[isrt];
    const int jj = (int)(mykey & (N_PTS - 1));
    const int jo = (int)OI[jj];
    float dx = F[io*3+0] - F[jo*3+0];
    float dy = F[io*3+1] - F[jo*3+1];
    float dz = F[io*3+2] - F[jo*3+2];
    float sv = sqrtf(fmaf(dx, dx, fmaf(dy, dy, dz * dz)));
    #pragma unroll
    for (int d = 1; d < 64; d <<= 1) sv += __shfl_xor(sv, d, 64);
    return (lane == 0) ? sv : 0.0f;
}

// ---------------- mega: static 2-unit waves, no atomics in work path ----------------
// R7 post-mortem: work-steal ctr = 12288 DEPENDENT same-address global atomics
// (serialized at one L2 channel) + persistent-loop state spilled (WRITE 4.9MB).
// R8: static mapping, straight-line two-unit code per wave (no loop state),
// R7's prefetch walks, R6's tight seeds, per-block LDS accumulate -> 1 global
// atomic per block. Wave w handles {w, w+6144}: every wave gets units from
// both halves of the Morton-ordered unit space -> heavy clusters spread.
__global__ __launch_bounds__(256, 4) void mega_kernel(
        const float4* __restrict__ ws, const float* __restrict__ flow,
        const unsigned* __restrict__ oidx, float* __restrict__ out) {
    __shared__ float bacc;
    const int tid = threadIdx.x, bx = blockIdx.x;
    const int lane = tid & 63, wv = tid >> 6;
    if (tid == 0) bacc = 0.0f;
    __syncthreads();

    const int w = bx * 4 + wv;                    // 0 .. 6143
    float acc = 0.0f;
    if (w < NUNIT_C) {
        // unit w: chamfer; unit w+6144: smooth id w+2048
        acc += chamfer_unit(ws, w, lane) * (1.0f / (float)(BATCH * N_PTS));
        acc += smooth_unit(ws, oidx, flow, w + 2048, lane)
               * (0.125f / ((float)BATCH * N_PTS * KNN));
    } else {
        // units w, w+6144: smooth ids w-4096 and w+2048
        acc += smooth_unit(ws, oidx, flow, w - 4096, lane)
               * (0.125f / ((float)BATCH * N_PTS * KNN));
        acc += smooth_unit(ws, oidx, flow, w + 2048, lane)
               * (0.125f / ((float)BATCH * N_PTS * KNN));
    }
    if (lane == 0) atomicAdd(&bacc, acc);         // LDS atomic, 4 per block
    __syncthreads();
    if (tid == 0) atomicAdd(out, bacc);           // 1536 global adds total
}

extern "C" void kernel_launch(void* const* d_in, const int* in_sizes, int n_in,
                              void* d_out, int out_size, void* d_ws, size_t ws_size,
                              hipStream_t stream) {
    const float* pc1  = (const float*)d_in[0];
    const float* pc2  = (const float*)d_in[1];
    const float* flow = (const float*)d_in[2];
    float* out = (float*)d_out;
    float4* ws4 = (float4*)d_ws;                  // needs ~857 KiB
    unsigned* oidx = (unsigned*)(ws4 + WS_OIDX);

    pack_sort_kernel<<<dim3(6), 512, 0, stream>>>(pc1, pc2, flow, ws4, oidx);
    mega_kernel<<<dim3(NBLOCKS), 256, 0, stream>>>(ws4, flow, oidx, out);
}

// Round 9
// 136.182 us; speedup vs baseline: 2.5166x; 1.6944x over previous
//
#include <hip/hip_runtime.h>

#define N_PTS 8192
#define BATCH 2
#define KNN 8
#define NBLK_C 1024                // chamfer: 4 combos x 256 row-blocks (32 rows)
#define NBLK_S 2048                // smooth: 2 batches x 1024 groups (8 points, 2/wave)
#define NBLOCKS (NBLK_C + NBLK_S)  // 3072, role-interleaved by bx%3

// packed workspace layout: float4(x,y,z,|p|^2) per point
//  arr 0,1: pc2[b]            (chamfer candidates dir0 / rows dir1)
//  arr 2,3: pc1[b]+flow[b]    (warped: rows dir0 / candidates dir1)
//  arr 4,5: pc1[b]            (smooth rows+candidates)
// total 6*8192*16B = 768 KiB in d_ws
#define ARR_PC2  0
#define ARR_WARP 2
#define ARR_PC1  4

// R8 post-mortem / why this file is the R5 kernel verbatim:
// The slab-pruning arc (R6: 102us, R7: 267us, R8: 168us) cut eval work ~5x
// but replaced a throughput regime (streaming, 88% VALU issue) with a
// latency regime (scattered dependent slab loads, <=43% VALU; R7 atomic
// serialization; R8 scratch demotion, WRITE 13.9MB). Pre-committed rule:
// mega > 80us => pruning structurally beaten by streaming here. Reverted.
// This kernel: mega 87.5us, VALUBusy 88%, no spill, no bank conflicts --
// within ~12% of the algorithm's VALU issue floor (268M+134M evals x ~3.5
// VALU/eval). Five micro-levers measured <=5% each (R0-R5 ladder).

// ---------------- helpers ----------------
__device__ __forceinline__ void ce(unsigned &x, unsigned &y) {
    unsigned lo = min(x, y), hi = max(x, y); x = lo; y = hi;
}

__device__ __forceinline__ void insert4(unsigned o[4], unsigned key) {
    unsigned n0 = min(o[0], key);
    unsigned n1 = max(o[0], min(o[1], key));
    unsigned n2 = max(o[1], min(o[2], key));
    unsigned n3 = max(o[2], min(o[3], key));
    o[0]=n0; o[1]=n1; o[2]=n2; o[3]=n3;
}

__device__ __forceinline__ void merge_stage8(unsigned m[8], int d) {
    unsigned p[8], c[8];
    #pragma unroll
    for (int k = 0; k < 8; ++k) p[k] = (unsigned)__shfl_xor((int)m[k], d, 64);
    #pragma unroll
    for (int k = 0; k < 8; ++k) c[k] = min(m[k], p[7-k]);
    ce(c[0],c[4]); ce(c[1],c[5]); ce(c[2],c[6]); ce(c[3],c[7]);
    ce(c[0],c[2]); ce(c[1],c[3]); ce(c[4],c[6]); ce(c[5],c[7]);
    ce(c[0],c[1]); ce(c[2],c[3]); ce(c[4],c[5]); ce(c[6],c[7]);
    #pragma unroll
    for (int k = 0; k < 8; ++k) m[k] = c[k];
}

__device__ __forceinline__ void merge64(unsigned m[8]) {
    merge_stage8(m, 1); merge_stage8(m, 2); merge_stage8(m, 4);
    merge_stage8(m, 8); merge_stage8(m, 16); merge_stage8(m, 32);
}

// ---------------- pack: 6 float4 arrays, one-time warp-add + |p|^2 ----------------
__global__ __launch_bounds__(256) void pack_kernel(
        const float* __restrict__ pc1, const float* __restrict__ pc2,
        const float* __restrict__ flow, float4* __restrict__ ws) {
    const int t = blockIdx.x * 256 + threadIdx.x;   // 0 .. 6*8192-1
    const int arr = t >> 13, i = t & (N_PTS - 1);
    const int bb = arr & 1;
    const size_t base = (size_t)bb * N_PTS * 3 + (size_t)i * 3;
    float x, y, z;
    if (arr < 2)      { x = pc2[base+0];              y = pc2[base+1];              z = pc2[base+2]; }
    else if (arr < 4) { x = pc1[base+0] + flow[base+0];
                        y = pc1[base+1] + flow[base+1];
                        z = pc1[base+2] + flow[base+2]; }
    else              { x = pc1[base+0];              y = pc1[base+1];              z = pc1[base+2]; }
    ws[t] = make_float4(x, y, z, fmaf(x, x, fmaf(y, y, z * z)));
}

// ---------------- mega: role-interleaved C|S blocks, barrier-free scans ----------------
// role = bx%3: 2 smooth + 1 chamfer per triple -> chamfer's dense independent
// FMA fills smooth's latency bubbles on the same SIMD. Smooth at 2 rows/wave
// -> 8192 S-waves = 100% occupancy ceiling. launch_bounds(256,4): 128-VGPR
// no-spill guarantee (R1 lesson: (256,8) halves the budget and spills).
__global__ __launch_bounds__(256, 4) void mega_kernel(
        const float4* __restrict__ ws, const float* __restrict__ flow,
        float* __restrict__ out) {
    __shared__ float psum[4];
    const int tid = threadIdx.x, bx = blockIdx.x;
    const int lane = tid & 63, wv = tid >> 6;
    const int ri = bx / 3, role = bx % 3;   // ri in [0,1024)

    if (role == 2) {
        // ============ role C: chamfer, 32 rows/block (8/thread), full scan ============
        const int z = ri >> 8, bb = z & 1, dir = z >> 1;
        const int cb = ri & 255;
        const float4* rows = ws + (size_t)((dir == 0 ? ARR_WARP : ARR_PC2) + bb) * N_PTS;
        const float4* cand = ws + (size_t)((dir == 0 ? ARR_PC2 : ARR_WARP) + bb) * N_PTS;
        const int rbase = cb * 32 + wv * 8;      // wave-uniform 8-row group

        float mx[8], my[8], mz[8], bmin[8];
        #pragma unroll
        for (int k = 0; k < 8; ++k) {
            float4 q = rows[rbase + k];          // wave-uniform -> broadcast load
            mx[k] = -2.0f * q.x; my[k] = -2.0f * q.y; mz[k] = -2.0f * q.z;
            bmin[k] = __builtin_inff();
        }

        // 64 paired iters: 2 dwordx4 feed 32 evals; mins fold to v_min3_f32
        #pragma unroll 2
        for (int j = 0; j < N_PTS; j += 128) {
            float4 qa = cand[j + lane];
            float4 qb = cand[j + 64 + lane];
            #pragma unroll
            for (int k = 0; k < 8; ++k) {
                float sa = fmaf(mx[k], qa.x, fmaf(my[k], qa.y, fmaf(mz[k], qa.z, qa.w)));
                float sb = fmaf(mx[k], qb.x, fmaf(my[k], qb.y, fmaf(mz[k], qb.z, qb.w)));
                bmin[k] = fminf(fminf(bmin[k], sa), sb);
            }
        }

        #pragma unroll
        for (int k = 0; k < 8; ++k) {
            #pragma unroll
            for (int d = 1; d < 64; d <<= 1)
                bmin[k] = fminf(bmin[k], __shfl_xor(bmin[k], d, 64));
        }
        if (lane == 0) {
            float val = 0.0f;
            #pragma unroll
            for (int k = 0; k < 8; ++k) {
                // p2 reconstructed: mx=-2px -> p2 = 0.25*(mx^2+my^2+mz^2)
                float p2k = 0.25f * fmaf(mx[k], mx[k], fmaf(my[k], my[k], mz[k] * mz[k]));
                val += sqrtf(fmaxf(bmin[k] + p2k, 0.0f));
            }
            psum[wv] = val;
        }
        __syncthreads();
        if (tid == 0) {
            float ch = psum[0] + psum[1] + psum[2] + psum[3];
            atomicAdd(out, ch * (1.0f / (float)(BATCH * N_PTS)));
        }
    } else {
        // ============ role S: smooth, 8 points/block (2/wave), gated KNN ============
        const int sbx = ri * 2 + role;           // [0, 2048)
        const int b  = sbx >> 10;
        const int sx = sbx & 1023;
        const int i0w = sx * 8 + wv * 2;
        const float4* cand = ws + (size_t)(ARR_PC1 + b) * N_PTS;
        const float* F = flow + (size_t)b * N_PTS * 3;

        float mx[2], my[2], mz[2], p2[2], gr[2];
        unsigned thr[2], o[2][4];
        #pragma unroll
        for (int r = 0; r < 2; ++r) {
            float4 q = cand[i0w + r];            // wave-uniform
            mx[r] = -2.0f * q.x; my[r] = -2.0f * q.y; mz[r] = -2.0f * q.z;
            p2[r] = q.w;
            gr[r] = __builtin_inff();
            thr[r] = 0xFFFFFFFFu;
            #pragma unroll
            for (int k = 0; k < 4; ++k) o[r][k] = 0xFFFFFFFFu;
        }

        // tight thr: per-32-half true top-4 via 5-stage butterfly;
        // bound = max of the two halves' 4th keys (8 real keys >= true 8th)
        auto update_thr = [&]() {
            #pragma unroll
            for (int r = 0; r < 2; ++r) {
                unsigned m0 = o[r][0], m1 = o[r][1], m2 = o[r][2], m3 = o[r][3];
                #pragma unroll
                for (int d = 1; d <= 16; d <<= 1) {
                    unsigned q0 = (unsigned)__shfl_xor((int)m0, d, 64);
                    unsigned q1 = (unsigned)__shfl_xor((int)m1, d, 64);
                    unsigned q2 = (unsigned)__shfl_xor((int)m2, d, 64);
                    unsigned q3 = (unsigned)__shfl_xor((int)m3, d, 64);
                    unsigned c0 = min(m0, q3), c1 = min(m1, q2);
                    unsigned c2 = min(m2, q1), c3 = min(m3, q0);
                    ce(c0, c2); ce(c1, c3); ce(c0, c1); ce(c2, c3);
                    m0 = c0; m1 = c1; m2 = c2; m3 = c3;
                }
                unsigned bound = max(m3, (unsigned)__shfl_xor((int)m3, 32, 64));
                thr[r] = min(thr[r], bound);
                // +2 truncation-buckets slack: gate passes superset of key<=thr
                float thr_up = __uint_as_float((thr[r] & 0xFFFFE000u) + 0x4000u);
                gr[r] = thr_up - p2[r];
            }
        };

        // paired slabs: 2 loads in flight, ONE uniform branch per row per 128 cands
        auto gated_span = [&](int j0, int j1) {
            #pragma unroll 2
            for (int j = j0; j < j1; j += 128) {
                float4 qa = cand[j + lane];
                float4 qb = cand[j + 64 + lane];
                int ja = j + lane, jb = j + 64 + lane;
                float sa[2], sb[2];
                #pragma unroll
                for (int r = 0; r < 2; ++r) {
                    sa[r] = fmaf(mx[r], qa.x, fmaf(my[r], qa.y, fmaf(mz[r], qa.z, qa.w)));
                    sb[r] = fmaf(mx[r], qb.x, fmaf(my[r], qb.y, fmaf(mz[r], qb.z, qb.w)));
                }
                #pragma unroll
                for (int r = 0; r < 2; ++r) {
                    if (__any(fminf(sa[r], sb[r]) <= gr[r])) {
                        float da = fmaxf(sa[r] + p2[r], 0.0f);
                        unsigned ka = (__float_as_uint(da) & 0xFFFFE000u) | (unsigned)ja;
                        ka = (ja == i0w + r) ? 0xFFFFFFFFu : ka;
                        insert4(o[r], ka);
                        float db = fmaxf(sb[r] + p2[r], 0.0f);
                        unsigned kb = (__float_as_uint(db) & 0xFFFFE000u) | (unsigned)jb;
                        kb = (jb == i0w + r) ? 0xFFFFFFFFu : kb;
                        insert4(o[r], kb);
                    }
                }
            }
        };

        // chunk 0 (1024 cands) unconditional sample, then gated spans;
        // thr refresh after 1024 / 2048 / 4096 (proven schedule)
        #pragma unroll 2
        for (int j = 0; j < 1024; j += 128) {
            float4 qa = cand[j + lane];
            float4 qb = cand[j + 64 + lane];
            int ja = j + lane, jb = j + 64 + lane;
            #pragma unroll
            for (int r = 0; r < 2; ++r) {
                float sa = fmaf(mx[r], qa.x, fmaf(my[r], qa.y, fmaf(mz[r], qa.z, qa.w)));
                float da = fmaxf(sa + p2[r], 0.0f);
                unsigned ka = (__float_as_uint(da) & 0xFFFFE000u) | (unsigned)ja;
                ka = (ja == i0w + r) ? 0xFFFFFFFFu : ka;
                insert4(o[r], ka);
                float sb = fmaf(mx[r], qb.x, fmaf(my[r], qb.y, fmaf(mz[r], qb.z, qb.w)));
                float db = fmaxf(sb + p2[r], 0.0f);
                unsigned kb = (__float_as_uint(db) & 0xFFFFE000u) | (unsigned)jb;
                kb = (jb == i0w + r) ? 0xFFFFFFFFu : kb;
                insert4(o[r], kb);
            }
        }
        update_thr();
        gated_span(1024, 2048); update_thr();
        gated_span(2048, 4096); update_thr();
        gated_span(4096, N_PTS);

        // final per-point top-8 + epilogue; sel = (point, k) over 16 slots,
        // lane dup x4 -> scale /4
        const int sel = lane & 15;
        const int pr = sel >> 3, kk = sel & 7;
        unsigned mykey = 0xFFFFFFFFu;
        #pragma unroll
        for (int r = 0; r < 2; ++r) {
            unsigned m[8] = {o[r][0], o[r][1], o[r][2], o[r][3],
                             0xFFFFFFFFu, 0xFFFFFFFFu, 0xFFFFFFFFu, 0xFFFFFFFFu};
            merge64(m);
            if (pr == r) {
                unsigned k2 = m[0];
                #pragma unroll
                for (int t = 1; t < 8; ++t) k2 = (kk == t) ? m[t] : k2;
                mykey = k2;
            }
        }
        const int i = i0w + pr;
        const int j = (int)(mykey & (N_PTS - 1));
        float dx = F[i*3+0] - F[j*3+0];
        float dy = F[i*3+1] - F[j*3+1];
        float dz = F[i*3+2] - F[j*3+2];
        float sv = sqrtf(fmaf(dx, dx, fmaf(dy, dy, dz * dz)));
        #pragma unroll
        for (int d = 1; d < 64; d <<= 1) sv += __shfl_xor(sv, d, 64);
        if (lane == 0) psum[wv] = sv;
        __syncthreads();

        if (tid == 0) {
            float sm = psum[0] + psum[1] + psum[2] + psum[3];
            // smooth: W=0.5, /4 lane dup -> 0.125
            atomicAdd(out, sm * (0.125f / ((float)BATCH * N_PTS * KNN)));
        }
    }
}

extern "C" void kernel_launch(void* const* d_in, const int* in_sizes, int n_in,
                              void* d_out, int out_size, void* d_ws, size_t ws_size,
                              hipStream_t stream) {
    const float* pc1  = (const float*)d_in[0];
    const float* pc2  = (const float*)d_in[1];
    const float* flow = (const float*)d_in[2];
    float* out = (float*)d_out;
    float4* ws4 = (float4*)d_ws;   // needs 6*8192*16B = 768 KiB

    pack_kernel<<<dim3(6 * N_PTS / 256), 256, 0, stream>>>(pc1, pc2, flow, ws4);
    mega_kernel<<<dim3(NBLOCKS), 256, 0, stream>>>(ws4, flow, out);
}